// Round 5
// baseline (365.525 us; speedup 1.0000x reference)
//
#include <hip/hip_runtime.h>

// MoE router: logits = hs @ W^T + b ; probs = softmax(logits) ; top-2.
// Outputs (concatenated in d_out, all float32):
//   [0, 2T)        flat_expert_index (written as float values 0..7)
//   [2T, 4T)       expert_weights (top-2 probs)
//   [4T, 4T+8T)    router_logits
// T = tokens = 16384, H = 4096, E = 8.

constexpr int E   = 8;
constexpr int H   = 4096;
constexpr int H4  = H / 4;          // float4 count per row = 1024
constexpr int TPW = 4;              // tokens per wave
constexpr int WPB = 4;              // waves per block (256 threads)
constexpr int TPB = TPW * WPB;      // 16 tokens per block

__global__ __launch_bounds__(256, 4)
void router_kernel(const float* __restrict__ hs,
                   const float* __restrict__ Wm,
                   const float* __restrict__ bias,
                   float* __restrict__ out,
                   int tokens) {
  const int lane = threadIdx.x & 63;
  const int wv   = threadIdx.x >> 6;
  const int tok0 = blockIdx.x * TPB + wv * TPW;

  const float4* __restrict__ hs4 = reinterpret_cast<const float4*>(hs);
  const float4* __restrict__ W4  = reinterpret_cast<const float4*>(Wm);

  // Clamped per-token row bases (safe if tokens not divisible by TPB).
  const float4* hrow[TPW];
#pragma unroll
  for (int t = 0; t < TPW; ++t) {
    int tk = tok0 + t;
    if (tk >= tokens) tk = tokens - 1;
    hrow[t] = hs4 + (size_t)tk * H4;
  }

  float acc[TPW][E];
#pragma unroll
  for (int t = 0; t < TPW; ++t)
#pragma unroll
    for (int e = 0; e < E; ++e) acc[t][e] = 0.f;

  // 16 iterations: wave covers 256 contiguous floats per row per iter.
#pragma unroll 2
  for (int i = 0; i < H4 / 64; ++i) {
    const int k4 = i * 64 + lane;
    float4 h[TPW];
#pragma unroll
    for (int t = 0; t < TPW; ++t) h[t] = hrow[t][k4];
#pragma unroll
    for (int e = 0; e < E; ++e) {
      const float4 w = W4[(size_t)e * H4 + k4];
#pragma unroll
      for (int t = 0; t < TPW; ++t)
        acc[t][e] += h[t].x * w.x + h[t].y * w.y + h[t].z * w.z + h[t].w * w.w;
    }
  }

  // Butterfly reduce all 32 partials across the 64-lane wave.
#pragma unroll
  for (int off = 32; off >= 1; off >>= 1)
#pragma unroll
    for (int t = 0; t < TPW; ++t)
#pragma unroll
      for (int e = 0; e < E; ++e)
        acc[t][e] += __shfl_xor(acc[t][e], off, 64);

  // Lanes 0..3 finish one token each: bias + softmax + top-2 + stores.
  if (lane < TPW) {
    const int t   = lane;
    const int tok = tok0 + t;
    if (tok < tokens) {
      float lg[E];
      float m = -3.4e38f;
#pragma unroll
      for (int e = 0; e < E; ++e) {
        lg[e] = acc[t][e] + bias[e];
        m = fmaxf(m, lg[e]);
      }
      float p[E];
      float s = 0.f;
#pragma unroll
      for (int e = 0; e < E; ++e) { p[e] = expf(lg[e] - m); s += p[e]; }
      const float inv = 1.f / s;
#pragma unroll
      for (int e = 0; e < E; ++e) p[e] *= inv;

      // top-2, strict '>' keeps lowest index on ties (matches jax.lax.top_k)
      int i0 = 0; float p0 = p[0];
#pragma unroll
      for (int e = 1; e < E; ++e) if (p[e] > p0) { p0 = p[e]; i0 = e; }
      int i1 = (i0 == 0) ? 1 : 0; float p1 = p[i1];
#pragma unroll
      for (int e = 0; e < E; ++e)
        if (e != i0 && p[e] > p1) { p1 = p[e]; i1 = e; }

      // stores
      out[2 * tok]     = (float)i0;
      out[2 * tok + 1] = (float)i1;
      float* ow = out + 2 * (size_t)tokens;
      ow[2 * tok]     = p0;
      ow[2 * tok + 1] = p1;
      float4* o4 = reinterpret_cast<float4*>(out + 4 * (size_t)tokens + (size_t)tok * E);
      o4[0] = make_float4(lg[0], lg[1], lg[2], lg[3]);
      o4[1] = make_float4(lg[4], lg[5], lg[6], lg[7]);
    }
  }
}

extern "C" void kernel_launch(void* const* d_in, const int* in_sizes, int n_in,
                              void* d_out, int out_size, void* d_ws, size_t ws_size,
                              hipStream_t stream) {
  const float* hs = (const float*)d_in[0];
  const float* Wm = (const float*)d_in[1];
  const float* b  = (const float*)d_in[2];
  float* out      = (float*)d_out;
  const int tokens = in_sizes[0] / H;          // 4*4096 = 16384
  const int blocks = (tokens + TPB - 1) / TPB; // 1024
  router_kernel<<<blocks, 256, 0, stream>>>(hs, Wm, b, out, tokens);
}